// Round 1
// baseline (652.312 us; speedup 1.0000x reference)
//
#include <hip/hip_runtime.h>
#include <hip/hip_bf16.h>

// Problem constants (fixed by the reference setup_inputs)
#define NB    2
#define FIN   32
#define TT    8
#define NN    20000
#define BT    16      // NB*TT
#define CC    32      // channel width of both aggregation passes

// ---------------------------------------------------------------------------
// 1) degree + in-degree-count histogram over edges (targets = col = ei[E+e])
__global__ void deg_cnt_kernel(const int* __restrict__ ei, const float* __restrict__ ew,
                               float* __restrict__ deg, int* __restrict__ cnt, int E) {
    int e = blockIdx.x * 256 + threadIdx.x;
    if (e >= E) return;
    int c = ei[E + e];
    atomicAdd(&deg[c], ew[e]);
    atomicAdd(&cnt[c], 1);
}

// 2) per-node: add self-loop weight 1.0, deg_inv_sqrt, self-loop norm = 1/deg
__global__ void node_kernel(const float* __restrict__ deg, float* __restrict__ dis,
                            float* __restrict__ selfw, int N) {
    int n = blockIdx.x * 256 + threadIdx.x;
    if (n >= N) return;
    float d = deg[n] + 1.0f;          // self loop contributes weight 1 -> deg >= 1 > 0
    dis[n]   = rsqrtf(d);
    selfw[n] = 1.0f / d;              // dis[n]*1*dis[n]
}

// 3) exclusive prefix scan of cnt -> offs[N+1], single block of 1024
__global__ __launch_bounds__(1024) void scan_kernel(const int* __restrict__ cnt,
                                                    int* __restrict__ offs, int n) {
    __shared__ int buf[1024];
    int carry = 0;
    for (int base = 0; base < n; base += 1024) {
        int i = base + threadIdx.x;
        int v = (i < n) ? cnt[i] : 0;
        buf[threadIdx.x] = v;
        __syncthreads();
        for (int off = 1; off < 1024; off <<= 1) {
            int t = (threadIdx.x >= off) ? buf[threadIdx.x - off] : 0;
            __syncthreads();
            buf[threadIdx.x] += t;
            __syncthreads();
        }
        if (i < n) offs[i] = carry + buf[threadIdx.x] - v;
        carry += buf[1023];
        __syncthreads();   // protect buf before next chunk overwrites it
    }
    if (threadIdx.x == 0) offs[n] = carry;
}

// 4) scatter edges into CSR rows keyed by target (col); w = dis[row]*ew*dis[col]
__global__ void fill_kernel(const int* __restrict__ ei, const float* __restrict__ ew,
                            const float* __restrict__ dis, const int* __restrict__ offs,
                            int* __restrict__ fill, int* __restrict__ csr_src,
                            float* __restrict__ csr_w, int E) {
    int e = blockIdx.x * 256 + threadIdx.x;
    if (e >= E) return;
    int r = ei[e], c = ei[E + e];
    float w = dis[r] * ew[e] * dis[c];
    int p = offs[c] + atomicAdd(&fill[c], 1);
    csr_src[p] = r;
    csr_w[p]   = w;
}

// 5) rowsum of A (for the b1 pass-through term): rowsum[n] = selfw[n] + sum(csr_w row)
__global__ void rowsum_kernel(const int* __restrict__ offs, const float* __restrict__ csr_w,
                              const float* __restrict__ selfw, float* __restrict__ rowsum, int N) {
    int n = blockIdx.x * 256 + threadIdx.x;
    if (n >= N) return;
    float s = selfw[n];
    int e1 = offs[n + 1];
    for (int e = offs[n]; e < e1; ++e) s += csr_w[e];
    rowsum[n] = s;
}

// 6) W12 = W1 @ W2  (32x64 @ 64x32), bb = b1 @ W2 — one block of 1024
__global__ __launch_bounds__(1024) void w12_kernel(const float* __restrict__ W1,
                                                   const float* __restrict__ W2,
                                                   const float* __restrict__ b1,
                                                   float* __restrict__ W12,
                                                   float* __restrict__ bb) {
    int f = threadIdx.x >> 5, c = threadIdx.x & 31;
    float acc = 0.f;
    for (int k = 0; k < 64; ++k) acc += W1[f * 64 + k] * W2[k * 32 + c];
    W12[f * 32 + c] = acc;
    if (f == 0) {
        float a2 = 0.f;
        for (int k = 0; k < 64; ++k) a2 += b1[k] * W2[k * 32 + c];
        bb[c] = a2;
    }
}

// 7) transpose x[B,F,T,N] -> xt[BT, N, 32] (channels-last), LDS-tiled
__global__ void transpose_kernel(const float* __restrict__ x, float* __restrict__ xt, int N) {
    __shared__ float tile[128][33];
    int bt = blockIdx.y;
    int b = bt >> 3, t = bt & 7;
    int n0 = blockIdx.x * 128;
    // read: x[(b*256 + f*8 + t)*N + n], coalesced over n
    for (int i = 0; i < 16; ++i) {
        int idx = i * 256 + threadIdx.x;   // 0..4095
        int f = idx >> 7;                  // 0..31
        int nl = idx & 127;
        int n = n0 + nl;
        float v = (n < N) ? x[(size_t)(b * 256 + f * 8 + t) * N + n] : 0.f;
        tile[nl][f] = v;
    }
    __syncthreads();
    // write: xt[(bt*N + n)*32 + f], coalesced
    for (int i = 0; i < 16; ++i) {
        int idx = i * 256 + threadIdx.x;
        int nl = idx >> 5;
        int f = idx & 31;
        int n = n0 + nl;
        if (n < N) xt[((size_t)bt * N + n) * 32 + f] = tile[nl][f];
    }
}

// 8) gather-aggregate: dst[bt,n,c] = selfw[n]*src[bt,n,c] + sum_e w_e * src[bt,src_e,c]
//    half-wave (32 lanes = 32 channels) per node -> each edge is one 128B coalesced read
__global__ void agg_kernel(const float* __restrict__ src, float* __restrict__ dst,
                           const int* __restrict__ offs, const int* __restrict__ csr_src,
                           const float* __restrict__ csr_w, const float* __restrict__ selfw,
                           int N) {
    int bt = blockIdx.y;
    int n = blockIdx.x * 8 + (threadIdx.x >> 5);
    int c = threadIdx.x & 31;
    if (n >= N) return;
    const float* sbase = src + (size_t)bt * N * CC;
    float acc = selfw[n] * sbase[(size_t)n * CC + c];
    int e1 = offs[n + 1];
    for (int e = offs[n]; e < e1; ++e) {
        int s = csr_src[e];
        acc += csr_w[e] * sbase[(size_t)s * CC + c];
    }
    dst[(size_t)bt * N * CC + (size_t)n * CC + c] = acc;
}

// 9) epilogue: out[b,c,t,n] = tanh( Z[bt,n,:]@W12[:,c] + rowsum[n]*bb[c] + b2[c] )
__global__ void final_kernel(const float* __restrict__ Z, const float* __restrict__ W12,
                             const float* __restrict__ bb, const float* __restrict__ b2,
                             const float* __restrict__ rowsum, float* __restrict__ out, int N) {
    __shared__ float w[32][32];
    __shared__ float zt[64][33];
    __shared__ float bbs[32], b2s[32], rs[64];
    int bt = blockIdx.y;
    int b = bt >> 3, t = bt & 7;
    int n0 = blockIdx.x * 64;
    int tid = threadIdx.x;
    for (int i = tid; i < 1024; i += 256) w[i >> 5][i & 31] = W12[i];
    if (tid < 32) { bbs[tid] = bb[tid]; b2s[tid] = b2[tid]; }
    if (tid < 64) { int n = n0 + tid; rs[tid] = (n < N) ? rowsum[n] : 0.f; }
    for (int i = tid; i < 2048; i += 256) {
        int nl = i >> 5, f = i & 31;
        int n = n0 + nl;
        zt[nl][f] = (n < N) ? Z[((size_t)bt * N + n) * CC + f] : 0.f;
    }
    __syncthreads();
    for (int i = tid; i < 2048; i += 256) {
        int c = i >> 6, nl = i & 63;   // c uniform per wave -> w[f][c] broadcasts
        int n = n0 + nl;
        if (n < N) {
            float acc = b2s[c] + rs[nl] * bbs[c];
            #pragma unroll
            for (int f = 0; f < 32; ++f) acc += zt[nl][f] * w[f][c];
            out[(((size_t)b * 32 + c) * TT + t) * (size_t)N + n] = tanhf(acc);
        }
    }
}

extern "C" void kernel_launch(void* const* d_in, const int* in_sizes, int n_in,
                              void* d_out, int out_size, void* d_ws, size_t ws_size,
                              hipStream_t stream) {
    const float* x  = (const float*)d_in[0];
    const int*   ei = (const int*)d_in[1];
    const float* ew = (const float*)d_in[2];
    const float* W1 = (const float*)d_in[3];
    const float* b1 = (const float*)d_in[4];
    const float* W2 = (const float*)d_in[5];
    const float* b2 = (const float*)d_in[6];
    float* out = (float*)d_out;

    const int N = NN;
    const int E = in_sizes[2];

    // workspace layout
    size_t NF = (size_t)BT * N * CC;        // 10.24M floats
    float* xt = (float*)d_ws;               // also reused as Z
    float* Y  = xt + NF;
    char* p = (char*)(Y + NF);
    int*   csr_src = (int*)p;    p += (size_t)E * 4;
    float* csr_w   = (float*)p;  p += (size_t)E * 4;
    float* deg     = (float*)p;  p += (size_t)N * 4;   // deg, cnt, fill contiguous (one memset)
    int*   cnt     = (int*)p;    p += (size_t)N * 4;
    int*   fill    = (int*)p;    p += (size_t)N * 4;
    float* dis     = (float*)p;  p += (size_t)N * 4;
    float* selfw   = (float*)p;  p += (size_t)N * 4;
    float* rowsum  = (float*)p;  p += (size_t)N * 4;
    int*   offs    = (int*)p;    p += (size_t)(N + 1) * 4;
    float* W12     = (float*)p;  p += 1024 * 4;
    float* bb      = (float*)p;

    hipMemsetAsync(deg, 0, (size_t)N * 4 * 3, stream);

    int ge = (E + 255) / 256;
    int gn = (N + 255) / 256;
    deg_cnt_kernel<<<ge, 256, 0, stream>>>(ei, ew, deg, cnt, E);
    node_kernel<<<gn, 256, 0, stream>>>(deg, dis, selfw, N);
    scan_kernel<<<1, 1024, 0, stream>>>(cnt, offs, N);
    fill_kernel<<<ge, 256, 0, stream>>>(ei, ew, dis, offs, fill, csr_src, csr_w, E);
    rowsum_kernel<<<gn, 256, 0, stream>>>(offs, csr_w, selfw, rowsum, N);
    w12_kernel<<<1, 1024, 0, stream>>>(W1, W2, b1, W12, bb);

    dim3 gtr((N + 127) / 128, BT);
    transpose_kernel<<<gtr, 256, 0, stream>>>(x, xt, N);

    dim3 gagg((N + 7) / 8, BT);
    agg_kernel<<<gagg, 256, 0, stream>>>(xt, Y, offs, csr_src, csr_w, selfw, N);   // Y = A@X
    agg_kernel<<<gagg, 256, 0, stream>>>(Y, xt, offs, csr_src, csr_w, selfw, N);   // Z = A@Y (reuse xt)

    dim3 gfin((N + 63) / 64, BT);
    final_kernel<<<gfin, 256, 0, stream>>>(xt, W12, bb, b2, rowsum, out, N);
}

// Round 2
// 372.970 us; speedup vs baseline: 1.7490x; 1.7490x over previous
//
#include <hip/hip_runtime.h>
#include <hip/hip_bf16.h>

// Problem constants (fixed by the reference setup_inputs)
#define NB    2
#define FIN   32
#define TT    8
#define NN    20000
#define BT    16      // NB*TT
#define CC    32      // channel width of both aggregation passes

// ---------------------------------------------------------------------------
// 1) degree + in-degree-count histogram over edges (targets = col = ei[E+e])
__global__ void deg_cnt_kernel(const int* __restrict__ ei, const float* __restrict__ ew,
                               float* __restrict__ deg, int* __restrict__ cnt, int E) {
    int e = blockIdx.x * 256 + threadIdx.x;
    if (e >= E) return;
    int c = ei[E + e];
    atomicAdd(&deg[c], ew[e]);
    atomicAdd(&cnt[c], 1);
}

// 2) per-node: add self-loop weight 1.0, deg_inv_sqrt, self-loop norm = 1/deg
__global__ void node_kernel(const float* __restrict__ deg, float* __restrict__ dis,
                            float* __restrict__ selfw, int N) {
    int n = blockIdx.x * 256 + threadIdx.x;
    if (n >= N) return;
    float d = deg[n] + 1.0f;          // self loop contributes weight 1 -> deg >= 1 > 0
    dis[n]   = rsqrtf(d);
    selfw[n] = 1.0f / d;              // dis[n]*1*dis[n]
}

// 3) exclusive prefix scan of cnt -> offs[N+1], single block of 1024
__global__ __launch_bounds__(1024) void scan_kernel(const int* __restrict__ cnt,
                                                    int* __restrict__ offs, int n) {
    __shared__ int buf[1024];
    int carry = 0;
    for (int base = 0; base < n; base += 1024) {
        int i = base + threadIdx.x;
        int v = (i < n) ? cnt[i] : 0;
        buf[threadIdx.x] = v;
        __syncthreads();
        for (int off = 1; off < 1024; off <<= 1) {
            int t = (threadIdx.x >= off) ? buf[threadIdx.x - off] : 0;
            __syncthreads();
            buf[threadIdx.x] += t;
            __syncthreads();
        }
        if (i < n) offs[i] = carry + buf[threadIdx.x] - v;
        carry += buf[1023];
        __syncthreads();   // protect buf before next chunk overwrites it
    }
    if (threadIdx.x == 0) offs[n] = carry;
}

// 4) scatter edges into CSR rows keyed by target (col); interleaved (src, w)
//    w = dis[row]*ew*dis[col]
__global__ void fill_kernel(const int* __restrict__ ei, const float* __restrict__ ew,
                            const float* __restrict__ dis, const int* __restrict__ offs,
                            int* __restrict__ fill, int2* __restrict__ csr, int E) {
    int e = blockIdx.x * 256 + threadIdx.x;
    if (e >= E) return;
    int r = ei[e], c = ei[E + e];
    float w = dis[r] * ew[e] * dis[c];
    int p = offs[c] + atomicAdd(&fill[c], 1);
    csr[p] = make_int2(r, __float_as_int(w));
}

// 5) rowsum of A (for the b1 pass-through term): rowsum[n] = selfw[n] + sum(csr_w row)
__global__ void rowsum_kernel(const int* __restrict__ offs, const int2* __restrict__ csr,
                              const float* __restrict__ selfw, float* __restrict__ rowsum, int N) {
    int n = blockIdx.x * 256 + threadIdx.x;
    if (n >= N) return;
    float s = selfw[n];
    int e1 = offs[n + 1];
    for (int e = offs[n]; e < e1; ++e) s += __int_as_float(csr[e].y);
    rowsum[n] = s;
}

// 6) W12 = W1 @ W2  (32x64 @ 64x32), bb = b1 @ W2 — one block of 1024
__global__ __launch_bounds__(1024) void w12_kernel(const float* __restrict__ W1,
                                                   const float* __restrict__ W2,
                                                   const float* __restrict__ b1,
                                                   float* __restrict__ W12,
                                                   float* __restrict__ bb) {
    int f = threadIdx.x >> 5, c = threadIdx.x & 31;
    float acc = 0.f;
    for (int k = 0; k < 64; ++k) acc += W1[f * 64 + k] * W2[k * 32 + c];
    W12[f * 32 + c] = acc;
    if (f == 0) {
        float a2 = 0.f;
        for (int k = 0; k < 64; ++k) a2 += b1[k] * W2[k * 32 + c];
        bb[c] = a2;
    }
}

// 7) transpose x[B,F,T,N] -> xt[BT, N, 32] (channels-last), LDS-tiled
__global__ void transpose_kernel(const float* __restrict__ x, float* __restrict__ xt, int N) {
    __shared__ float tile[128][33];
    int bt = blockIdx.y;
    int b = bt >> 3, t = bt & 7;
    int n0 = blockIdx.x * 128;
    for (int i = 0; i < 16; ++i) {
        int idx = i * 256 + threadIdx.x;   // 0..4095
        int f = idx >> 7;                  // 0..31
        int nl = idx & 127;
        int n = n0 + nl;
        float v = (n < N) ? x[(size_t)(b * 256 + f * 8 + t) * N + n] : 0.f;
        tile[nl][f] = v;
    }
    __syncthreads();
    for (int i = 0; i < 16; ++i) {
        int idx = i * 256 + threadIdx.x;
        int nl = idx >> 5;
        int f = idx & 31;
        int n = n0 + nl;
        if (n < N) xt[((size_t)bt * N + n) * 32 + f] = tile[nl][f];
    }
}

// 8) gather-aggregate over ALL 16 bt planes in one pass.
//    One 64-lane wave per node: lane = (c in [0,32), h in {0,1}); each lane
//    accumulates 8 planes (bt = h*8+q). Per edge: one 8B (src,w) load + 8
//    independent 128B-coalesced gathers; unroll-by-2 -> ~16 outstanding loads.
__global__ __launch_bounds__(256) void agg16_kernel(const float* __restrict__ src,
                                                    float* __restrict__ dst,
                                                    const int* __restrict__ offs,
                                                    const int2* __restrict__ csr,
                                                    const float* __restrict__ selfw,
                                                    int N) {
    int n = (blockIdx.x * 256 + threadIdx.x) >> 6;
    if (n >= N) return;
    int lane = threadIdx.x & 63;
    int c = lane & 31;
    int h = lane >> 5;
    const size_t PS = (size_t)NN * CC;            // per-bt plane stride (floats)
    const float* base  = src + (size_t)h * 8 * PS + c;
    float*       dbase = dst + (size_t)h * 8 * PS + c;
    float sw = selfw[n];
    size_t noff = (size_t)n * CC;
    float acc[8];
#pragma unroll
    for (int q = 0; q < 8; ++q) acc[q] = sw * base[q * PS + noff];
    int e = offs[n], e1 = offs[n + 1];
    for (; e + 2 <= e1; e += 2) {
        int2 vA = csr[e];
        int2 vB = csr[e + 1];
        size_t oA = (size_t)vA.x * CC;
        size_t oB = (size_t)vB.x * CC;
        float wA = __int_as_float(vA.y);
        float wB = __int_as_float(vB.y);
        float tA[8], tB[8];
#pragma unroll
        for (int q = 0; q < 8; ++q) tA[q] = base[q * PS + oA];
#pragma unroll
        for (int q = 0; q < 8; ++q) tB[q] = base[q * PS + oB];
#pragma unroll
        for (int q = 0; q < 8; ++q) acc[q] += wA * tA[q];
#pragma unroll
        for (int q = 0; q < 8; ++q) acc[q] += wB * tB[q];
    }
    if (e < e1) {
        int2 vA = csr[e];
        size_t oA = (size_t)vA.x * CC;
        float wA = __int_as_float(vA.y);
#pragma unroll
        for (int q = 0; q < 8; ++q) acc[q] += wA * base[q * PS + oA];
    }
#pragma unroll
    for (int q = 0; q < 8; ++q) dbase[q * PS + noff] = acc[q];
}

// 9) epilogue: out[b,c,t,n] = tanh( Z[bt,n,:]@W12[:,c] + rowsum[n]*bb[c] + b2[c] )
__global__ void final_kernel(const float* __restrict__ Z, const float* __restrict__ W12,
                             const float* __restrict__ bb, const float* __restrict__ b2,
                             const float* __restrict__ rowsum, float* __restrict__ out, int N) {
    __shared__ float w[32][32];
    __shared__ float zt[64][33];
    __shared__ float bbs[32], b2s[32], rs[64];
    int bt = blockIdx.y;
    int b = bt >> 3, t = bt & 7;
    int n0 = blockIdx.x * 64;
    int tid = threadIdx.x;
    for (int i = tid; i < 1024; i += 256) w[i >> 5][i & 31] = W12[i];
    if (tid < 32) { bbs[tid] = bb[tid]; b2s[tid] = b2[tid]; }
    if (tid < 64) { int n = n0 + tid; rs[tid] = (n < N) ? rowsum[n] : 0.f; }
    for (int i = tid; i < 2048; i += 256) {
        int nl = i >> 5, f = i & 31;
        int n = n0 + nl;
        zt[nl][f] = (n < N) ? Z[((size_t)bt * N + n) * CC + f] : 0.f;
    }
    __syncthreads();
    for (int i = tid; i < 2048; i += 256) {
        int c = i >> 6, nl = i & 63;   // c uniform per wave -> w[f][c] broadcasts
        int n = n0 + nl;
        if (n < N) {
            float acc = b2s[c] + rs[nl] * bbs[c];
            #pragma unroll
            for (int f = 0; f < 32; ++f) acc += zt[nl][f] * w[f][c];
            out[(((size_t)b * 32 + c) * TT + t) * (size_t)N + n] = tanhf(acc);
        }
    }
}

extern "C" void kernel_launch(void* const* d_in, const int* in_sizes, int n_in,
                              void* d_out, int out_size, void* d_ws, size_t ws_size,
                              hipStream_t stream) {
    const float* x  = (const float*)d_in[0];
    const int*   ei = (const int*)d_in[1];
    const float* ew = (const float*)d_in[2];
    const float* W1 = (const float*)d_in[3];
    const float* b1 = (const float*)d_in[4];
    const float* W2 = (const float*)d_in[5];
    const float* b2 = (const float*)d_in[6];
    float* out = (float*)d_out;

    const int N = NN;
    const int E = in_sizes[2];

    // workspace layout
    size_t NF = (size_t)BT * N * CC;        // 10.24M floats
    float* xt = (float*)d_ws;               // also reused as Z
    float* Y  = xt + NF;
    char* p = (char*)(Y + NF);
    int2*  csr     = (int2*)p;   p += (size_t)E * 8;
    float* deg     = (float*)p;  p += (size_t)N * 4;   // deg, cnt, fill contiguous (one memset)
    int*   cnt     = (int*)p;    p += (size_t)N * 4;
    int*   fill    = (int*)p;    p += (size_t)N * 4;
    float* dis     = (float*)p;  p += (size_t)N * 4;
    float* selfw   = (float*)p;  p += (size_t)N * 4;
    float* rowsum  = (float*)p;  p += (size_t)N * 4;
    int*   offs    = (int*)p;    p += (size_t)(N + 1) * 4;
    float* W12     = (float*)p;  p += 1024 * 4;
    float* bb      = (float*)p;

    hipMemsetAsync(deg, 0, (size_t)N * 4 * 3, stream);

    int ge = (E + 255) / 256;
    int gn = (N + 255) / 256;
    deg_cnt_kernel<<<ge, 256, 0, stream>>>(ei, ew, deg, cnt, E);
    node_kernel<<<gn, 256, 0, stream>>>(deg, dis, selfw, N);
    scan_kernel<<<1, 1024, 0, stream>>>(cnt, offs, N);
    fill_kernel<<<ge, 256, 0, stream>>>(ei, ew, dis, offs, fill, csr, E);
    rowsum_kernel<<<gn, 256, 0, stream>>>(offs, csr, selfw, rowsum, N);
    w12_kernel<<<1, 1024, 0, stream>>>(W1, W2, b1, W12, bb);

    dim3 gtr((N + 127) / 128, BT);
    transpose_kernel<<<gtr, 256, 0, stream>>>(x, xt, N);

    int gagg = (N * 64 + 255) / 256;   // one 64-lane wave per node
    agg16_kernel<<<gagg, 256, 0, stream>>>(xt, Y, offs, csr, selfw, N);   // Y = A@X
    agg16_kernel<<<gagg, 256, 0, stream>>>(Y, xt, offs, csr, selfw, N);   // Z = A@Y

    dim3 gfin((N + 63) / 64, BT);
    final_kernel<<<gfin, 256, 0, stream>>>(xt, W12, bb, b2, rowsum, out, N);
}